// Round 8
// baseline (735.674 us; speedup 1.0000x reference)
//
#include <hip/hip_runtime.h>

#define HH 512
#define WW 512
#define BB 2
#define CKXY 0.3125f   /* COMPACT / sqrt(H*W/NSUP) = 10/32 */
#define HW (HH*WW)

// conv 3x3: 32x32 tile, 256 threads, 4 px/thread (quadrants).
// Channels staged through LDS in chunks of <=5: LDS = 5*34*40*4 = 27.2 KB
// -> 5 blocks/CU (20 waves/CU) vs round-4's 2 blocks (8 waves).
// Next chunk's global loads are issued into REGISTERS before computing the
// current chunk (async-stage split), then ds_written after a barrier.
template<int CIN, int COUT, bool RELU>
__global__ __launch_bounds__(256) void conv_chunk(const float* __restrict__ in,
    const float* __restrict__ w, const float* __restrict__ bias,
    float* __restrict__ out) {
  constexpr int CH = 5;
  constexpr int NCHUNK = (CIN + CH - 1) / CH;
  const int bx = blockIdx.x, by = blockIdx.y, b = blockIdx.z;
  const int tid = threadIdx.x;
  const int tx = tid & 15, ty = tid >> 4;
  const int gy0 = by * 32, gx0 = bx * 32;
  __shared__ float sIn[CH][34][40];
  const float* inb = in + (size_t)b * CIN * HW;

  const int ir = tid >> 5;    // staging row base 0..7
  const int icol = tid & 31;  // staging col

  float ri[CH][4];
  float rh[3];

  auto load_regs = [&](int chunk) {
    const int c0 = chunk * CH;
    const int nch = (CIN - c0) < CH ? (CIN - c0) : CH;
    #pragma unroll
    for (int cg = 0; cg < CH; ++cg) {
      if (cg < nch) {
        #pragma unroll
        for (int p = 0; p < 4; ++p) {
          int r = ir + p * 8;
          ri[cg][p] = inb[(c0 + cg) * HW + (gy0 + r) * WW + gx0 + icol];
        }
      }
    }
    #pragma unroll
    for (int h = 0; h < 3; ++h) {
      int idx = tid + 256 * h;
      if (idx < nch * 132) {
        int cg = idx / 132, rem = idx - cg * 132;
        int ly, lx;
        if (rem < 34)       { ly = 0;  lx = rem; }
        else if (rem < 68)  { ly = 33; lx = rem - 34; }
        else if (rem < 100) { lx = 0;  ly = rem - 68 + 1; }
        else                { lx = 33; ly = rem - 100 + 1; }
        int gy = gy0 + ly - 1, gx = gx0 + lx - 1;
        float v = 0.f;
        if ((unsigned)gy < HH && (unsigned)gx < WW)
          v = inb[(c0 + cg) * HW + gy * WW + gx];
        rh[h] = v;
      }
    }
  };

  auto write_lds = [&](int chunk) {
    const int c0 = chunk * CH;
    const int nch = (CIN - c0) < CH ? (CIN - c0) : CH;
    #pragma unroll
    for (int cg = 0; cg < CH; ++cg) {
      if (cg < nch) {
        #pragma unroll
        for (int p = 0; p < 4; ++p)
          sIn[cg][ir + p * 8 + 1][icol + 1] = ri[cg][p];
      }
    }
    #pragma unroll
    for (int h = 0; h < 3; ++h) {
      int idx = tid + 256 * h;
      if (idx < nch * 132) {
        int cg = idx / 132, rem = idx - cg * 132;
        int ly, lx;
        if (rem < 34)       { ly = 0;  lx = rem; }
        else if (rem < 68)  { ly = 33; lx = rem - 34; }
        else if (rem < 100) { lx = 0;  ly = rem - 68 + 1; }
        else                { lx = 33; ly = rem - 100 + 1; }
        sIn[cg][ly][lx] = rh[h];
      }
    }
  };

  float acc[COUT][4];
  #pragma unroll
  for (int co = 0; co < COUT; ++co) {
    float bv = bias[co];
    #pragma unroll
    for (int q = 0; q < 4; ++q) acc[co][q] = bv;
  }

  load_regs(0);
  write_lds(0);
  __syncthreads();
  #pragma unroll
  for (int chunk = 0; chunk < NCHUNK; ++chunk) {
    if (chunk + 1 < NCHUNK) load_regs(chunk + 1);  // issue early, hide latency
    const int c0 = chunk * CH;
    const int nch = (CIN - c0) < CH ? (CIN - c0) : CH;
    for (int cg = 0; cg < nch; ++cg) {
      const int ci = c0 + cg;
      #pragma unroll
      for (int q = 0; q < 4; ++q) {
        const int r0 = ty + ((q >> 1) << 4), cc0 = tx + ((q & 1) << 4);
        float v[9];
        #pragma unroll
        for (int t = 0; t < 9; ++t) v[t] = sIn[cg][r0 + t / 3][cc0 + t % 3];
        #pragma unroll
        for (int co = 0; co < COUT; ++co) {
          #pragma unroll
          for (int t = 0; t < 9; ++t)
            acc[co][q] = fmaf(v[t], w[(co * CIN + ci) * 9 + t], acc[co][q]);
        }
      }
    }
    if (chunk + 1 < NCHUNK) {
      __syncthreads();        // all reads of this chunk done
      write_lds(chunk + 1);
      __syncthreads();
    }
  }

  float* outb = out + (size_t)b * COUT * HW;
  #pragma unroll
  for (int co = 0; co < COUT; ++co) {
    #pragma unroll
    for (int q = 0; q < 4; ++q) {
      int y = gy0 + ty + ((q >> 1) << 4), x = gx0 + tx + ((q & 1) << 4);
      float r = RELU ? fmaxf(acc[co][q], 0.f) : acc[co][q];
      outb[co * HW + y * WW + x] = r;
    }
  }
}

// ---- final conv (10->5) + imfeat build + cent0 reduction (block == cell)
// imfeat channels: 0..4 s1, 5..7 X, 8 x*ck, 9 y*ck
__global__ __launch_bounds__(256) void conv_final_chunk(const float* __restrict__ in,
    const float* __restrict__ w, const float* __restrict__ bias,
    const float* __restrict__ X, float* __restrict__ imfeat,
    float* __restrict__ cent0) {
  constexpr int CH = 5;
  const int bx = blockIdx.x, by = blockIdx.y, b = blockIdx.z;
  const int tid = threadIdx.x;
  const int tx = tid & 15, ty = tid >> 4;
  const int gy0 = by * 32, gx0 = bx * 32;
  __shared__ float sIn[CH][34][40];
  const float* inb = in + (size_t)b * 10 * HW;

  const int ir = tid >> 5;
  const int icol = tid & 31;

  float ri[CH][4];
  float rh[3];

  auto load_regs = [&](int chunk) {
    const int c0 = chunk * CH;
    #pragma unroll
    for (int cg = 0; cg < CH; ++cg) {
      #pragma unroll
      for (int p = 0; p < 4; ++p) {
        int r = ir + p * 8;
        ri[cg][p] = inb[(c0 + cg) * HW + (gy0 + r) * WW + gx0 + icol];
      }
    }
    #pragma unroll
    for (int h = 0; h < 3; ++h) {
      int idx = tid + 256 * h;
      if (idx < CH * 132) {
        int cg = idx / 132, rem = idx - cg * 132;
        int ly, lx;
        if (rem < 34)       { ly = 0;  lx = rem; }
        else if (rem < 68)  { ly = 33; lx = rem - 34; }
        else if (rem < 100) { lx = 0;  ly = rem - 68 + 1; }
        else                { lx = 33; ly = rem - 100 + 1; }
        int gy = gy0 + ly - 1, gx = gx0 + lx - 1;
        float v = 0.f;
        if ((unsigned)gy < HH && (unsigned)gx < WW)
          v = inb[(c0 + cg) * HW + gy * WW + gx];
        rh[h] = v;
      }
    }
  };

  auto write_lds = [&]() {
    #pragma unroll
    for (int cg = 0; cg < CH; ++cg) {
      #pragma unroll
      for (int p = 0; p < 4; ++p)
        sIn[cg][ir + p * 8 + 1][icol + 1] = ri[cg][p];
    }
    #pragma unroll
    for (int h = 0; h < 3; ++h) {
      int idx = tid + 256 * h;
      if (idx < CH * 132) {
        int cg = idx / 132, rem = idx - cg * 132;
        int ly, lx;
        if (rem < 34)       { ly = 0;  lx = rem; }
        else if (rem < 68)  { ly = 33; lx = rem - 34; }
        else if (rem < 100) { lx = 0;  ly = rem - 68 + 1; }
        else                { lx = 33; ly = rem - 100 + 1; }
        sIn[cg][ly][lx] = rh[h];
      }
    }
  };

  float acc[5][4];
  #pragma unroll
  for (int co = 0; co < 5; ++co) {
    float bv = bias[co];
    #pragma unroll
    for (int q = 0; q < 4; ++q) acc[co][q] = bv;
  }

  load_regs(0);
  write_lds();
  __syncthreads();
  #pragma unroll
  for (int chunk = 0; chunk < 2; ++chunk) {
    if (chunk == 0) load_regs(1);
    for (int cg = 0; cg < CH; ++cg) {
      const int ci = chunk * CH + cg;
      #pragma unroll
      for (int q = 0; q < 4; ++q) {
        const int r0 = ty + ((q >> 1) << 4), cc0 = tx + ((q & 1) << 4);
        float v[9];
        #pragma unroll
        for (int t = 0; t < 9; ++t) v[t] = sIn[cg][r0 + t / 3][cc0 + t % 3];
        #pragma unroll
        for (int co = 0; co < 5; ++co) {
          #pragma unroll
          for (int t = 0; t < 9; ++t)
            acc[co][q] = fmaf(v[t], w[(co * 10 + ci) * 9 + t], acc[co][q]);
        }
      }
    }
    if (chunk == 0) {
      __syncthreads();
      write_lds();
      __syncthreads();
    }
  }

  float* ob = imfeat + (size_t)b * 10 * HW;
  const float* Xb = X + (size_t)b * 3 * HW;
  float cs[10];
  #pragma unroll
  for (int ch = 0; ch < 10; ++ch) cs[ch] = 0.f;
  #pragma unroll
  for (int q = 0; q < 4; ++q) {
    int y = gy0 + ty + ((q >> 1) << 4), x = gx0 + tx + ((q & 1) << 4);
    int p = y * WW + x;
    #pragma unroll
    for (int co = 0; co < 5; ++co) { float v = acc[co][q]; ob[co * HW + p] = v; cs[co] += v; }
    #pragma unroll
    for (int c = 0; c < 3; ++c) { float v = Xb[c * HW + p]; ob[(5 + c) * HW + p] = v; cs[5 + c] += v; }
    float xc = (float)x * CKXY, yc = (float)y * CKXY;
    ob[8 * HW + p] = xc; cs[8] += xc;
    ob[9 * HW + p] = yc; cs[9] += yc;
  }
  #pragma unroll
  for (int off = 32; off; off >>= 1) {
    #pragma unroll
    for (int ch = 0; ch < 10; ++ch) cs[ch] += __shfl_down(cs[ch], off);
  }
  __shared__ float sP[4][10];
  const int wave = tid >> 6;
  if ((tid & 63) == 0) {
    #pragma unroll
    for (int ch = 0; ch < 10; ++ch) sP[wave][ch] = cs[ch];
  }
  __syncthreads();
  if (tid < 10) {
    float s = sP[0][tid] + sP[1][tid] + sP[2][tid] + sP[3][tid];
    cent0[((b * 10 + tid) * 16 + by) * 16 + bx] = s * (1.0f / 1024.0f);
  }
}

// -------------------- SSN iteration: (optional in-block centroid) + aff + sums
__global__ __launch_bounds__(256) void iter2(const float* __restrict__ imfeat,
    const float* __restrict__ centIn, const float* __restrict__ numP,
    const float* __restrict__ denP, float* __restrict__ numO,
    float* __restrict__ denO, float* __restrict__ affO) {
  const int cx = blockIdx.x, cy = blockIdx.y, b = blockIdx.z;
  const int tid = threadIdx.x;
  __shared__ float sc[9][10];
  __shared__ float nb[9][11];
  if (centIn) {
    if (tid < 90) {
      int s = tid / 10, ch = tid - s * 10;
      int dr = s / 3 - 1, dc = s % 3 - 1;
      int r = min(max(cy + dr, 0), 15), c = min(max(cx + dc, 0), 15);
      sc[s][ch] = centIn[((b * 10 + ch) * 16 + r) * 16 + c];
    }
    __syncthreads();
  } else {
    if (tid < 99) {
      int s = tid / 11, j = tid - s * 11;
      int dr = s / 3 - 1, dc = s % 3 - 1;
      int r = min(max(cy + dr, 0), 15), c = min(max(cx + dc, 0), 15);
      float a = 0.f;
      #pragma unroll
      for (int rr = -1; rr <= 1; ++rr)
        #pragma unroll
        for (int cc = -1; cc <= 1; ++cc) {
          int R = r + rr, C = c + cc;
          if ((unsigned)R < 16u && (unsigned)C < 16u)
            a += (j < 10) ? numP[((b * 10 + j) * 16 + R) * 16 + C]
                          : denP[(b * 16 + R) * 16 + C];
        }
      nb[s][j] = a;
    }
    __syncthreads();
    if (tid < 90) {
      int s = tid / 10, ch = tid - s * 10;
      sc[s][ch] = nb[s][ch] / nb[s][10];
    }
    __syncthreads();
  }

  float accN[10];
  #pragma unroll
  for (int ch = 0; ch < 10; ++ch) accN[ch] = 0.f;
  float accD = 0.f;
  const int col = tid & 31, row0 = tid >> 5;
  for (int p = 0; p < 4; ++p) {
    const int y = cy * 32 + row0 + p * 8;
    const int x = cx * 32 + col;
    float f[10];
    #pragma unroll
    for (int ch = 0; ch < 10; ++ch)
      f[ch] = imfeat[((b * 10 + ch) * HH + y) * WW + x];
    float asum = 0.f;
    #pragma unroll
    for (int s = 0; s < 9; ++s) {
      float ss = 0.f;
      #pragma unroll
      for (int ch = 0; ch < 10; ++ch) { float d = f[ch] - sc[s][ch]; ss = fmaf(d, d, ss); }
      float a = __expf(-ss * (1.0f / 1000.0f));
      asum += a;
      if (affO) affO[((b * 9 + s) * HH + y) * WW + x] = a;
    }
    accD += asum;
    #pragma unroll
    for (int ch = 0; ch < 10; ++ch) accN[ch] = fmaf(f[ch], asum, accN[ch]);
  }
  #pragma unroll
  for (int off = 32; off; off >>= 1) {
    accD += __shfl_down(accD, off);
    #pragma unroll
    for (int ch = 0; ch < 10; ++ch) accN[ch] += __shfl_down(accN[ch], off);
  }
  __shared__ float sPart[4][11];
  const int wave = tid >> 6, lane = tid & 63;
  if (lane == 0) {
    #pragma unroll
    for (int ch = 0; ch < 10; ++ch) sPart[wave][ch] = accN[ch];
    sPart[wave][10] = accD;
  }
  __syncthreads();
  if (tid < 11) {
    float s = sPart[0][tid] + sPart[1][tid] + sPart[2][tid] + sPart[3][tid];
    if (tid < 10) numO[((b * 10 + tid) * 16 + cy) * 16 + cx] = s;
    else denO[(b * 16 + cy) * 16 + cx] = s;
  }
}

// ------------------------------- final cent = box3(num)/box3(den) -> output
__global__ __launch_bounds__(256) void cent_final(const float* __restrict__ num_bs,
    const float* __restrict__ den_bs, float* __restrict__ out_cent) {
  const int b = blockIdx.x;
  const int tid = threadIdx.x;
  const int cy = tid >> 4, cx = tid & 15;
  float den = 0.f;
  #pragma unroll
  for (int dr = -1; dr <= 1; ++dr)
    #pragma unroll
    for (int dc = -1; dc <= 1; ++dc) {
      int r = cy + dr, c = cx + dc;
      if ((unsigned)r < 16 && (unsigned)c < 16) den += den_bs[(b * 16 + r) * 16 + c];
    }
  #pragma unroll
  for (int ch = 0; ch < 10; ++ch) {
    float num = 0.f;
    #pragma unroll
    for (int dr = -1; dr <= 1; ++dr)
      #pragma unroll
      for (int dc = -1; dc <= 1; ++dc) {
        int r = cy + dr, c = cx + dc;
        if ((unsigned)r < 16 && (unsigned)c < 16)
          num += num_bs[((b * 10 + ch) * 16 + r) * 16 + c];
      }
    float invck = (ch >= 8) ? (1.0f / CKXY) : 1.0f;
    out_cent[((b * 10 + ch) * 16 + cy) * 16 + cx] = (num / den) * invck;
  }
}

// ---------------------------------------------------------------------------
extern "C" void kernel_launch(void* const* d_in, const int* in_sizes, int n_in,
                              void* d_out, int out_size, void* d_ws, size_t ws_size,
                              hipStream_t stream) {
  const float* X      = (const float*)d_in[0];
  const float* w0     = (const float*)d_in[1];
  const float* b0     = (const float*)d_in[2];
  const float* ws_mid = (const float*)d_in[3];
  const float* bs_mid = (const float*)d_in[4];
  const float* wf     = (const float*)d_in[5];
  const float* bf     = (const float*)d_in[6];
  float* out = (float*)d_out;

  const size_t plane = (size_t)BB * 10 * HW;  // 5,242,880 floats
  float* bufA  = (float*)d_ws;
  float* bufB  = bufA + plane;
  float* num0  = bufB + plane;
  float* den0  = num0 + BB * 10 * 256;
  float* num1  = den0 + BB * 256;
  float* den1  = num1 + BB * 10 * 256;
  float* centA = den1 + BB * 256;

  dim3 cgrid(16, 16, BB);   // 32x32 tiles
  conv_chunk<3, 10, true><<<cgrid, 256, 0, stream>>>(X, w0, b0, bufA);
  const float* cur = bufA;
  float* nxt = bufB;
  for (int l = 0; l < 8; ++l) {
    conv_chunk<10, 10, true><<<cgrid, 256, 0, stream>>>(cur, ws_mid + l * 900, bs_mid + l * 10, nxt);
    const float* t = cur; cur = nxt; nxt = (float*)t;
  }
  // cur == bufA after 8 swaps; imfeat -> bufB, cent0 -> centA
  conv_final_chunk<<<cgrid, 256, 0, stream>>>(cur, wf, bf, X, bufB, centA);

  float* aff_out = out + BB * 10 * 256;  // cent (5120) then aff
  float* nums[2] = {num0, num1};
  float* dens[2] = {den0, den1};
  for (int k = 0; k < 10; ++k) {
    iter2<<<cgrid, 256, 0, stream>>>(bufB,
        (k == 0) ? centA : nullptr,
        (k == 0) ? nullptr : nums[(k - 1) & 1],
        (k == 0) ? nullptr : dens[(k - 1) & 1],
        nums[k & 1], dens[k & 1],
        (k == 9) ? aff_out : nullptr);
  }
  cent_final<<<dim3(BB), 256, 0, stream>>>(nums[1], dens[1], out);
}

// Round 9
// 408.240 us; speedup vs baseline: 1.8021x; 1.8021x over previous
//
#include <hip/hip_runtime.h>

#define HH 512
#define WW 512
#define BB 2
#define CKXY 0.3125f   /* COMPACT / sqrt(H*W/NSUP) = 10/32 */
#define HW (HH*WW)

// ------------------------------------------------------------- conv 3x3, 32x32 tile
// Block: 1024 threads, 1 px/thread. LDS tile 34x40 (2-way bank access = free).
// 2 blocks/CU (54KB LDS) x 16 waves = 32 waves/CU. NO min-wave cap -> no spills.
template<int CIN, int COUT, bool RELU>
__global__ __launch_bounds__(1024) void conv3x3_t32(const float* __restrict__ in,
    const float* __restrict__ w, const float* __restrict__ bias,
    float* __restrict__ out) {
  const int bx = blockIdx.x, by = blockIdx.y, b = blockIdx.z;
  const int tid = threadIdx.x;
  const int xl = tid & 31, yl = tid >> 5;
  __shared__ float sIn[CIN][34][40];
  const float* inb = in + (size_t)b * CIN * HW;
  const int gy0 = by * 32, gx0 = bx * 32;
  // interior 32x32 per channel (exactly one load per thread per channel)
  #pragma unroll
  for (int ci = 0; ci < CIN; ++ci)
    sIn[ci][yl + 1][xl + 1] = inb[ci * HW + (gy0 + yl) * WW + gx0 + xl];
  // halo ring: 132 elems per channel
  for (int idx = tid; idx < CIN * 132; idx += 1024) {
    int ci = idx / 132, rem = idx - ci * 132;
    int ly, lx;
    if (rem < 34)       { ly = 0;  lx = rem; }
    else if (rem < 68)  { ly = 33; lx = rem - 34; }
    else if (rem < 100) { lx = 0;  ly = rem - 68 + 1; }
    else                { lx = 33; ly = rem - 100 + 1; }
    int gy = gy0 + ly - 1, gx = gx0 + lx - 1;
    float v = 0.f;
    if ((unsigned)gy < HH && (unsigned)gx < WW) v = inb[ci * HW + gy * WW + gx];
    sIn[ci][ly][lx] = v;
  }
  __syncthreads();

  float acc[COUT];
  #pragma unroll
  for (int co = 0; co < COUT; ++co) acc[co] = bias[co];
  #pragma unroll
  for (int ci = 0; ci < CIN; ++ci) {
    float v[9];
    #pragma unroll
    for (int t = 0; t < 9; ++t) v[t] = sIn[ci][yl + t / 3][xl + t % 3];
    #pragma unroll
    for (int co = 0; co < COUT; ++co) {
      #pragma unroll
      for (int t = 0; t < 9; ++t)
        acc[co] = fmaf(v[t], w[(co * CIN + ci) * 9 + t], acc[co]);
    }
  }
  float* outb = out + (size_t)b * COUT * HW;
  const int p = (gy0 + yl) * WW + gx0 + xl;
  #pragma unroll
  for (int co = 0; co < COUT; ++co) {
    float r = RELU ? fmaxf(acc[co], 0.f) : acc[co];
    outb[co * HW + p] = r;
  }
}

// ---------------------- final conv (10->5) + imfeat build + cent0 reduction
// One block == one SSN cell (32x32). imfeat channels: 0..4 s1, 5..7 X, 8 x*ck, 9 y*ck
__global__ __launch_bounds__(1024) void conv_final_t32(const float* __restrict__ in,
    const float* __restrict__ w, const float* __restrict__ bias,
    const float* __restrict__ X, float* __restrict__ imfeat,
    float* __restrict__ cent0) {
  const int bx = blockIdx.x, by = blockIdx.y, b = blockIdx.z;
  const int tid = threadIdx.x;
  const int xl = tid & 31, yl = tid >> 5;
  __shared__ float sIn[10][34][40];
  const float* inb = in + (size_t)b * 10 * HW;
  const int gy0 = by * 32, gx0 = bx * 32;
  #pragma unroll
  for (int ci = 0; ci < 10; ++ci)
    sIn[ci][yl + 1][xl + 1] = inb[ci * HW + (gy0 + yl) * WW + gx0 + xl];
  for (int idx = tid; idx < 10 * 132; idx += 1024) {
    int ci = idx / 132, rem = idx - ci * 132;
    int ly, lx;
    if (rem < 34)       { ly = 0;  lx = rem; }
    else if (rem < 68)  { ly = 33; lx = rem - 34; }
    else if (rem < 100) { lx = 0;  ly = rem - 68 + 1; }
    else                { lx = 33; ly = rem - 100 + 1; }
    int gy = gy0 + ly - 1, gx = gx0 + lx - 1;
    float v = 0.f;
    if ((unsigned)gy < HH && (unsigned)gx < WW) v = inb[ci * HW + gy * WW + gx];
    sIn[ci][ly][lx] = v;
  }
  __syncthreads();

  float acc[5];
  #pragma unroll
  for (int co = 0; co < 5; ++co) acc[co] = bias[co];
  #pragma unroll
  for (int ci = 0; ci < 10; ++ci) {
    float v[9];
    #pragma unroll
    for (int t = 0; t < 9; ++t) v[t] = sIn[ci][yl + t / 3][xl + t % 3];
    #pragma unroll
    for (int co = 0; co < 5; ++co) {
      #pragma unroll
      for (int t = 0; t < 9; ++t)
        acc[co] = fmaf(v[t], w[(co * 10 + ci) * 9 + t], acc[co]);
    }
  }
  float* ob = imfeat + (size_t)b * 10 * HW;
  const float* Xb = X + (size_t)b * 3 * HW;
  const int y = gy0 + yl, x = gx0 + xl;
  const int p = y * WW + x;
  float cs[10];
  #pragma unroll
  for (int co = 0; co < 5; ++co) { float v = acc[co]; ob[co * HW + p] = v; cs[co] = v; }
  #pragma unroll
  for (int c = 0; c < 3; ++c) { float v = Xb[c * HW + p]; ob[(5 + c) * HW + p] = v; cs[5 + c] = v; }
  float xc = (float)x * CKXY, yc = (float)y * CKXY;
  ob[8 * HW + p] = xc; cs[8] = xc;
  ob[9 * HW + p] = yc; cs[9] = yc;
  #pragma unroll
  for (int off = 32; off; off >>= 1) {
    #pragma unroll
    for (int ch = 0; ch < 10; ++ch) cs[ch] += __shfl_down(cs[ch], off);
  }
  __shared__ float sP[16][10];
  const int wave = tid >> 6;
  if ((tid & 63) == 0) {
    #pragma unroll
    for (int ch = 0; ch < 10; ++ch) sP[wave][ch] = cs[ch];
  }
  __syncthreads();
  if (tid < 10) {
    float s = 0.f;
    #pragma unroll
    for (int wv = 0; wv < 16; ++wv) s += sP[wv][tid];
    cent0[((b * 10 + tid) * 16 + by) * 16 + bx] = s * (1.0f / 1024.0f);
  }
}

// -------------------- SSN iteration: (optional in-block centroid) + aff + sums
__global__ __launch_bounds__(256) void iter2(const float* __restrict__ imfeat,
    const float* __restrict__ centIn, const float* __restrict__ numP,
    const float* __restrict__ denP, float* __restrict__ numO,
    float* __restrict__ denO, float* __restrict__ affO) {
  const int cx = blockIdx.x, cy = blockIdx.y, b = blockIdx.z;
  const int tid = threadIdx.x;
  __shared__ float sc[9][10];
  __shared__ float nb[9][11];
  if (centIn) {
    if (tid < 90) {
      int s = tid / 10, ch = tid - s * 10;
      int dr = s / 3 - 1, dc = s % 3 - 1;
      int r = min(max(cy + dr, 0), 15), c = min(max(cx + dc, 0), 15);
      sc[s][ch] = centIn[((b * 10 + ch) * 16 + r) * 16 + c];
    }
    __syncthreads();
  } else {
    if (tid < 99) {
      int s = tid / 11, j = tid - s * 11;
      int dr = s / 3 - 1, dc = s % 3 - 1;
      int r = min(max(cy + dr, 0), 15), c = min(max(cx + dc, 0), 15);
      float a = 0.f;
      #pragma unroll
      for (int rr = -1; rr <= 1; ++rr)
        #pragma unroll
        for (int cc = -1; cc <= 1; ++cc) {
          int R = r + rr, C = c + cc;
          if ((unsigned)R < 16u && (unsigned)C < 16u)
            a += (j < 10) ? numP[((b * 10 + j) * 16 + R) * 16 + C]
                          : denP[(b * 16 + R) * 16 + C];
        }
      nb[s][j] = a;
    }
    __syncthreads();
    if (tid < 90) {
      int s = tid / 10, ch = tid - s * 10;
      sc[s][ch] = nb[s][ch] / nb[s][10];
    }
    __syncthreads();
  }

  float accN[10];
  #pragma unroll
  for (int ch = 0; ch < 10; ++ch) accN[ch] = 0.f;
  float accD = 0.f;
  const int col = tid & 31, row0 = tid >> 5;
  for (int p = 0; p < 4; ++p) {
    const int y = cy * 32 + row0 + p * 8;
    const int x = cx * 32 + col;
    float f[10];
    #pragma unroll
    for (int ch = 0; ch < 10; ++ch)
      f[ch] = imfeat[((b * 10 + ch) * HH + y) * WW + x];
    float asum = 0.f;
    #pragma unroll
    for (int s = 0; s < 9; ++s) {
      float ss = 0.f;
      #pragma unroll
      for (int ch = 0; ch < 10; ++ch) { float d = f[ch] - sc[s][ch]; ss = fmaf(d, d, ss); }
      float a = __expf(-ss * (1.0f / 1000.0f));
      asum += a;
      if (affO) affO[((b * 9 + s) * HH + y) * WW + x] = a;
    }
    accD += asum;
    #pragma unroll
    for (int ch = 0; ch < 10; ++ch) accN[ch] = fmaf(f[ch], asum, accN[ch]);
  }
  #pragma unroll
  for (int off = 32; off; off >>= 1) {
    accD += __shfl_down(accD, off);
    #pragma unroll
    for (int ch = 0; ch < 10; ++ch) accN[ch] += __shfl_down(accN[ch], off);
  }
  __shared__ float sPart[4][11];
  const int wave = tid >> 6, lane = tid & 63;
  if (lane == 0) {
    #pragma unroll
    for (int ch = 0; ch < 10; ++ch) sPart[wave][ch] = accN[ch];
    sPart[wave][10] = accD;
  }
  __syncthreads();
  if (tid < 11) {
    float s = sPart[0][tid] + sPart[1][tid] + sPart[2][tid] + sPart[3][tid];
    if (tid < 10) numO[((b * 10 + tid) * 16 + cy) * 16 + cx] = s;
    else denO[(b * 16 + cy) * 16 + cx] = s;
  }
}

// ------------------------------- final cent = box3(num)/box3(den) -> output
__global__ __launch_bounds__(256) void cent_final(const float* __restrict__ num_bs,
    const float* __restrict__ den_bs, float* __restrict__ out_cent) {
  const int b = blockIdx.x;
  const int tid = threadIdx.x;
  const int cy = tid >> 4, cx = tid & 15;
  float den = 0.f;
  #pragma unroll
  for (int dr = -1; dr <= 1; ++dr)
    #pragma unroll
    for (int dc = -1; dc <= 1; ++dc) {
      int r = cy + dr, c = cx + dc;
      if ((unsigned)r < 16 && (unsigned)c < 16) den += den_bs[(b * 16 + r) * 16 + c];
    }
  #pragma unroll
  for (int ch = 0; ch < 10; ++ch) {
    float num = 0.f;
    #pragma unroll
    for (int dr = -1; dr <= 1; ++dr)
      #pragma unroll
      for (int dc = -1; dc <= 1; ++dc) {
        int r = cy + dr, c = cx + dc;
        if ((unsigned)r < 16 && (unsigned)c < 16)
          num += num_bs[((b * 10 + ch) * 16 + r) * 16 + c];
      }
    float invck = (ch >= 8) ? (1.0f / CKXY) : 1.0f;
    out_cent[((b * 10 + ch) * 16 + cy) * 16 + cx] = (num / den) * invck;
  }
}

// ---------------------------------------------------------------------------
extern "C" void kernel_launch(void* const* d_in, const int* in_sizes, int n_in,
                              void* d_out, int out_size, void* d_ws, size_t ws_size,
                              hipStream_t stream) {
  const float* X      = (const float*)d_in[0];
  const float* w0     = (const float*)d_in[1];
  const float* b0     = (const float*)d_in[2];
  const float* ws_mid = (const float*)d_in[3];
  const float* bs_mid = (const float*)d_in[4];
  const float* wf     = (const float*)d_in[5];
  const float* bf     = (const float*)d_in[6];
  float* out = (float*)d_out;

  const size_t plane = (size_t)BB * 10 * HW;  // 5,242,880 floats
  float* bufA  = (float*)d_ws;
  float* bufB  = bufA + plane;
  float* num0  = bufB + plane;
  float* den0  = num0 + BB * 10 * 256;
  float* num1  = den0 + BB * 256;
  float* den1  = num1 + BB * 10 * 256;
  float* centA = den1 + BB * 256;

  dim3 cgrid(16, 16, BB);   // 32x32 tiles
  conv3x3_t32<3, 10, true><<<cgrid, 1024, 0, stream>>>(X, w0, b0, bufA);
  const float* cur = bufA;
  float* nxt = bufB;
  for (int l = 0; l < 8; ++l) {
    conv3x3_t32<10, 10, true><<<cgrid, 1024, 0, stream>>>(cur, ws_mid + l * 900, bs_mid + l * 10, nxt);
    const float* t = cur; cur = nxt; nxt = (float*)t;
  }
  // cur == bufA after 8 swaps; imfeat -> bufB, cent0 -> centA
  conv_final_t32<<<cgrid, 1024, 0, stream>>>(cur, wf, bf, X, bufB, centA);

  float* aff_out = out + BB * 10 * 256;  // cent (5120) then aff
  float* nums[2] = {num0, num1};
  float* dens[2] = {den0, den1};
  for (int k = 0; k < 10; ++k) {
    iter2<<<cgrid, 256, 0, stream>>>(bufB,
        (k == 0) ? centA : nullptr,
        (k == 0) ? nullptr : nums[(k - 1) & 1],
        (k == 0) ? nullptr : dens[(k - 1) & 1],
        nums[k & 1], dens[k & 1],
        (k == 9) ? aff_out : nullptr);
  }
  cent_final<<<dim3(BB), 256, 0, stream>>>(nums[1], dens[1], out);
}

// Round 10
// 291.519 us; speedup vs baseline: 2.5236x; 1.4004x over previous
//
#include <hip/hip_runtime.h>

#define HH 512
#define WW 512
#define BB 2
#define CKXY 0.3125f   /* COMPACT / sqrt(H*W/NSUP) = 10/32 */
#define HW (HH*WW)

typedef short bf16x8 __attribute__((ext_vector_type(8)));
typedef float f32x4  __attribute__((ext_vector_type(4)));

__device__ __forceinline__ unsigned short f2bf(float f) {
  unsigned u = __float_as_uint(f);
  u += 0x7FFF + ((u >> 16) & 1);   // round-to-nearest-even
  return (unsigned short)(u >> 16);
}

// ---------------- MFMA mid conv 10->10 (+relu), 32x32 tile, 512 thr (8 waves)
// LDS: [34][34][16ch] bf16 = 37 KB -> 4 blocks/CU. Per 16-px tile: 5 MFMA
// (K=32 = 2 taps x 16 ci), A-frag = 1 ds_read_b128/lane, D -> float4 stores.
__global__ __launch_bounds__(512) void conv_mfma(const float* __restrict__ in,
    const float* __restrict__ w, const float* __restrict__ bias,
    float* __restrict__ out) {
  const int bx = blockIdx.x, by = blockIdx.y, b = blockIdx.z;
  const int tid = threadIdx.x;
  const int gy0 = by * 32, gx0 = bx * 32;
  __shared__ unsigned short sT[34 * 34 * 16];   // [py][px][ci(16)] bf16
  const float* inb = in + (size_t)b * 10 * HW;

  // ---- build weight fragments (B: k = tap_in_pair*16+ci, n = co)
  const int lane = tid & 63;
  const int g = lane >> 4;        // k-quarter 0..3
  const int co = lane & 15;       // output channel (cols 10..15 discarded)
  bf16x8 Bf[5];
  #pragma unroll
  for (int P = 0; P < 5; ++P) {
    #pragma unroll
    for (int j = 0; j < 8; ++j) {
      const int tap = 2 * P + (g >> 1);
      const int ci = ((g & 1) << 3) + j;
      unsigned short v = 0;
      if (co < 10 && ci < 10 && tap < 9)
        v = f2bf(w[(co * 10 + ci) * 9 + tap]);
      Bf[P][j] = (short)v;
    }
  }
  const float bs = (co < 10) ? bias[co] : 0.f;

  // ---- stage tile into LDS (bf16, ci-pairs packed, ci 10-15 zeroed)
  for (int p = tid; p < 34 * 34; p += 512) {
    const int ly = p / 34, lx = p - ly * 34;
    const int gy = gy0 + ly - 1, gx = gx0 + lx - 1;
    const bool ok = ((unsigned)gy < HH) && ((unsigned)gx < WW);
    const float* pp = inb + gy * WW + gx;
    unsigned u[5];
    #pragma unroll
    for (int c2 = 0; c2 < 5; ++c2) {
      float f0 = ok ? pp[(2 * c2) * HW] : 0.f;
      float f1 = ok ? pp[(2 * c2 + 1) * HW] : 0.f;
      u[c2] = (unsigned)f2bf(f0) | ((unsigned)f2bf(f1) << 16);
    }
    uint4* dst = reinterpret_cast<uint4*>(&sT[p * 16]);
    dst[0] = make_uint4(u[0], u[1], u[2], u[3]);
    dst[1] = make_uint4(u[4], 0u, 0u, 0u);
  }
  __syncthreads();

  // ---- compute: 64 px-tiles (32 rows x 2 halves), 8 per wave
  const int wave = tid >> 6;
  float* outb = out + (size_t)b * 10 * HW;
  for (int i = 0; i < 8; ++i) {
    const int t = wave * 8 + i;
    const int py = t >> 1;            // tile row 0..31
    const int pxb = (t & 1) << 4;     // 0 or 16
    f32x4 acc = {bs, bs, bs, bs};
    #pragma unroll
    for (int P = 0; P < 5; ++P) {
      int tap = 2 * P + (g >> 1);
      if (tap > 8) tap = 8;           // phantom tap: B=0 there
      const int dy = tap / 3 - 1, dx = tap % 3 - 1;
      const int m = lane & 15;        // A-row = pixel
      const int addr = ((py + 1 + dy) * 34 + (pxb + m + 1 + dx)) * 16 + ((g & 1) << 3);
      bf16x8 a = *reinterpret_cast<const bf16x8*>(&sT[addr]);
      acc = __builtin_amdgcn_mfma_f32_16x16x32_bf16(a, Bf[P], acc, 0, 0, 0);
    }
    if (co < 10) {
      const int y = gy0 + py;
      const int x = gx0 + pxb + (g << 2);   // D rows m = 4g+r
      float4 o;
      o.x = fmaxf(acc[0], 0.f);
      o.y = fmaxf(acc[1], 0.f);
      o.z = fmaxf(acc[2], 0.f);
      o.w = fmaxf(acc[3], 0.f);
      *reinterpret_cast<float4*>(&outb[co * HW + y * WW + x]) = o;
    }
  }
}

// ------------------------------------------------------------- conv 3x3, 32x32 tile
// (first layer, CIN=3) Block: 1024 threads, 1 px/thread. LDS 34x40 stride.
template<int CIN, int COUT, bool RELU>
__global__ __launch_bounds__(1024) void conv3x3_t32(const float* __restrict__ in,
    const float* __restrict__ w, const float* __restrict__ bias,
    float* __restrict__ out) {
  const int bx = blockIdx.x, by = blockIdx.y, b = blockIdx.z;
  const int tid = threadIdx.x;
  const int xl = tid & 31, yl = tid >> 5;
  __shared__ float sIn[CIN][34][40];
  const float* inb = in + (size_t)b * CIN * HW;
  const int gy0 = by * 32, gx0 = bx * 32;
  #pragma unroll
  for (int ci = 0; ci < CIN; ++ci)
    sIn[ci][yl + 1][xl + 1] = inb[ci * HW + (gy0 + yl) * WW + gx0 + xl];
  for (int idx = tid; idx < CIN * 132; idx += 1024) {
    int ci = idx / 132, rem = idx - ci * 132;
    int ly, lx;
    if (rem < 34)       { ly = 0;  lx = rem; }
    else if (rem < 68)  { ly = 33; lx = rem - 34; }
    else if (rem < 100) { lx = 0;  ly = rem - 68 + 1; }
    else                { lx = 33; ly = rem - 100 + 1; }
    int gy = gy0 + ly - 1, gx = gx0 + lx - 1;
    float v = 0.f;
    if ((unsigned)gy < HH && (unsigned)gx < WW) v = inb[ci * HW + gy * WW + gx];
    sIn[ci][ly][lx] = v;
  }
  __syncthreads();

  float acc[COUT];
  #pragma unroll
  for (int co = 0; co < COUT; ++co) acc[co] = bias[co];
  #pragma unroll
  for (int ci = 0; ci < CIN; ++ci) {
    float v[9];
    #pragma unroll
    for (int t = 0; t < 9; ++t) v[t] = sIn[ci][yl + t / 3][xl + t % 3];
    #pragma unroll
    for (int co = 0; co < COUT; ++co) {
      #pragma unroll
      for (int t = 0; t < 9; ++t)
        acc[co] = fmaf(v[t], w[(co * CIN + ci) * 9 + t], acc[co]);
    }
  }
  float* outb = out + (size_t)b * COUT * HW;
  const int p = (gy0 + yl) * WW + gx0 + xl;
  #pragma unroll
  for (int co = 0; co < COUT; ++co) {
    float r = RELU ? fmaxf(acc[co], 0.f) : acc[co];
    outb[co * HW + p] = r;
  }
}

// ---------------------- final conv (10->5) + imfeat build + cent0 reduction
__global__ __launch_bounds__(1024) void conv_final_t32(const float* __restrict__ in,
    const float* __restrict__ w, const float* __restrict__ bias,
    const float* __restrict__ X, float* __restrict__ imfeat,
    float* __restrict__ cent0) {
  const int bx = blockIdx.x, by = blockIdx.y, b = blockIdx.z;
  const int tid = threadIdx.x;
  const int xl = tid & 31, yl = tid >> 5;
  __shared__ float sIn[10][34][40];
  const float* inb = in + (size_t)b * 10 * HW;
  const int gy0 = by * 32, gx0 = bx * 32;
  #pragma unroll
  for (int ci = 0; ci < 10; ++ci)
    sIn[ci][yl + 1][xl + 1] = inb[ci * HW + (gy0 + yl) * WW + gx0 + xl];
  for (int idx = tid; idx < 10 * 132; idx += 1024) {
    int ci = idx / 132, rem = idx - ci * 132;
    int ly, lx;
    if (rem < 34)       { ly = 0;  lx = rem; }
    else if (rem < 68)  { ly = 33; lx = rem - 34; }
    else if (rem < 100) { lx = 0;  ly = rem - 68 + 1; }
    else                { lx = 33; ly = rem - 100 + 1; }
    int gy = gy0 + ly - 1, gx = gx0 + lx - 1;
    float v = 0.f;
    if ((unsigned)gy < HH && (unsigned)gx < WW) v = inb[ci * HW + gy * WW + gx];
    sIn[ci][ly][lx] = v;
  }
  __syncthreads();

  float acc[5];
  #pragma unroll
  for (int co = 0; co < 5; ++co) acc[co] = bias[co];
  #pragma unroll
  for (int ci = 0; ci < 10; ++ci) {
    float v[9];
    #pragma unroll
    for (int t = 0; t < 9; ++t) v[t] = sIn[ci][yl + t / 3][xl + t % 3];
    #pragma unroll
    for (int co = 0; co < 5; ++co) {
      #pragma unroll
      for (int t = 0; t < 9; ++t)
        acc[co] = fmaf(v[t], w[(co * 10 + ci) * 9 + t], acc[co]);
    }
  }
  float* ob = imfeat + (size_t)b * 10 * HW;
  const float* Xb = X + (size_t)b * 3 * HW;
  const int y = gy0 + yl, x = gx0 + xl;
  const int p = y * WW + x;
  float cs[10];
  #pragma unroll
  for (int co = 0; co < 5; ++co) { float v = acc[co]; ob[co * HW + p] = v; cs[co] = v; }
  #pragma unroll
  for (int c = 0; c < 3; ++c) { float v = Xb[c * HW + p]; ob[(5 + c) * HW + p] = v; cs[5 + c] = v; }
  float xc = (float)x * CKXY, yc = (float)y * CKXY;
  ob[8 * HW + p] = xc; cs[8] = xc;
  ob[9 * HW + p] = yc; cs[9] = yc;
  #pragma unroll
  for (int off = 32; off; off >>= 1) {
    #pragma unroll
    for (int ch = 0; ch < 10; ++ch) cs[ch] += __shfl_down(cs[ch], off);
  }
  __shared__ float sP[16][10];
  const int wave = tid >> 6;
  if ((tid & 63) == 0) {
    #pragma unroll
    for (int ch = 0; ch < 10; ++ch) sP[wave][ch] = cs[ch];
  }
  __syncthreads();
  if (tid < 10) {
    float s = 0.f;
    #pragma unroll
    for (int wv = 0; wv < 16; ++wv) s += sP[wv][tid];
    cent0[((b * 10 + tid) * 16 + by) * 16 + bx] = s * (1.0f / 1024.0f);
  }
}

// -------------------- SSN iteration: (optional in-block centroid) + aff + sums
__global__ __launch_bounds__(256) void iter2(const float* __restrict__ imfeat,
    const float* __restrict__ centIn, const float* __restrict__ numP,
    const float* __restrict__ denP, float* __restrict__ numO,
    float* __restrict__ denO, float* __restrict__ affO) {
  const int cx = blockIdx.x, cy = blockIdx.y, b = blockIdx.z;
  const int tid = threadIdx.x;
  __shared__ float sc[9][10];
  __shared__ float nb[9][11];
  if (centIn) {
    if (tid < 90) {
      int s = tid / 10, ch = tid - s * 10;
      int dr = s / 3 - 1, dc = s % 3 - 1;
      int r = min(max(cy + dr, 0), 15), c = min(max(cx + dc, 0), 15);
      sc[s][ch] = centIn[((b * 10 + ch) * 16 + r) * 16 + c];
    }
    __syncthreads();
  } else {
    if (tid < 99) {
      int s = tid / 11, j = tid - s * 11;
      int dr = s / 3 - 1, dc = s % 3 - 1;
      int r = min(max(cy + dr, 0), 15), c = min(max(cx + dc, 0), 15);
      float a = 0.f;
      #pragma unroll
      for (int rr = -1; rr <= 1; ++rr)
        #pragma unroll
        for (int cc = -1; cc <= 1; ++cc) {
          int R = r + rr, C = c + cc;
          if ((unsigned)R < 16u && (unsigned)C < 16u)
            a += (j < 10) ? numP[((b * 10 + j) * 16 + R) * 16 + C]
                          : denP[(b * 16 + R) * 16 + C];
        }
      nb[s][j] = a;
    }
    __syncthreads();
    if (tid < 90) {
      int s = tid / 10, ch = tid - s * 10;
      sc[s][ch] = nb[s][ch] / nb[s][10];
    }
    __syncthreads();
  }

  float accN[10];
  #pragma unroll
  for (int ch = 0; ch < 10; ++ch) accN[ch] = 0.f;
  float accD = 0.f;
  const int col = tid & 31, row0 = tid >> 5;
  for (int p = 0; p < 4; ++p) {
    const int y = cy * 32 + row0 + p * 8;
    const int x = cx * 32 + col;
    float f[10];
    #pragma unroll
    for (int ch = 0; ch < 10; ++ch)
      f[ch] = imfeat[((b * 10 + ch) * HH + y) * WW + x];
    float asum = 0.f;
    #pragma unroll
    for (int s = 0; s < 9; ++s) {
      float ss = 0.f;
      #pragma unroll
      for (int ch = 0; ch < 10; ++ch) { float d = f[ch] - sc[s][ch]; ss = fmaf(d, d, ss); }
      float a = __expf(-ss * (1.0f / 1000.0f));
      asum += a;
      if (affO) affO[((b * 9 + s) * HH + y) * WW + x] = a;
    }
    accD += asum;
    #pragma unroll
    for (int ch = 0; ch < 10; ++ch) accN[ch] = fmaf(f[ch], asum, accN[ch]);
  }
  #pragma unroll
  for (int off = 32; off; off >>= 1) {
    accD += __shfl_down(accD, off);
    #pragma unroll
    for (int ch = 0; ch < 10; ++ch) accN[ch] += __shfl_down(accN[ch], off);
  }
  __shared__ float sPart[4][11];
  const int wave = tid >> 6, lane = tid & 63;
  if (lane == 0) {
    #pragma unroll
    for (int ch = 0; ch < 10; ++ch) sPart[wave][ch] = accN[ch];
    sPart[wave][10] = accD;
  }
  __syncthreads();
  if (tid < 11) {
    float s = sPart[0][tid] + sPart[1][tid] + sPart[2][tid] + sPart[3][tid];
    if (tid < 10) numO[((b * 10 + tid) * 16 + cy) * 16 + cx] = s;
    else denO[(b * 16 + cy) * 16 + cx] = s;
  }
}

// ------------------------------- final cent = box3(num)/box3(den) -> output
__global__ __launch_bounds__(256) void cent_final(const float* __restrict__ num_bs,
    const float* __restrict__ den_bs, float* __restrict__ out_cent) {
  const int b = blockIdx.x;
  const int tid = threadIdx.x;
  const int cy = tid >> 4, cx = tid & 15;
  float den = 0.f;
  #pragma unroll
  for (int dr = -1; dr <= 1; ++dr)
    #pragma unroll
    for (int dc = -1; dc <= 1; ++dc) {
      int r = cy + dr, c = cx + dc;
      if ((unsigned)r < 16 && (unsigned)c < 16) den += den_bs[(b * 16 + r) * 16 + c];
    }
  #pragma unroll
  for (int ch = 0; ch < 10; ++ch) {
    float num = 0.f;
    #pragma unroll
    for (int dr = -1; dr <= 1; ++dr)
      #pragma unroll
      for (int dc = -1; dc <= 1; ++dc) {
        int r = cy + dr, c = cx + dc;
        if ((unsigned)r < 16 && (unsigned)c < 16)
          num += num_bs[((b * 10 + ch) * 16 + r) * 16 + c];
      }
    float invck = (ch >= 8) ? (1.0f / CKXY) : 1.0f;
    out_cent[((b * 10 + ch) * 16 + cy) * 16 + cx] = (num / den) * invck;
  }
}

// ---------------------------------------------------------------------------
extern "C" void kernel_launch(void* const* d_in, const int* in_sizes, int n_in,
                              void* d_out, int out_size, void* d_ws, size_t ws_size,
                              hipStream_t stream) {
  const float* X      = (const float*)d_in[0];
  const float* w0     = (const float*)d_in[1];
  const float* b0     = (const float*)d_in[2];
  const float* ws_mid = (const float*)d_in[3];
  const float* bs_mid = (const float*)d_in[4];
  const float* wf     = (const float*)d_in[5];
  const float* bf     = (const float*)d_in[6];
  float* out = (float*)d_out;

  const size_t plane = (size_t)BB * 10 * HW;  // 5,242,880 floats
  float* bufA  = (float*)d_ws;
  float* bufB  = bufA + plane;
  float* num0  = bufB + plane;
  float* den0  = num0 + BB * 10 * 256;
  float* num1  = den0 + BB * 256;
  float* den1  = num1 + BB * 10 * 256;
  float* centA = den1 + BB * 256;

  dim3 cgrid(16, 16, BB);   // 32x32 tiles
  conv3x3_t32<3, 10, true><<<cgrid, 1024, 0, stream>>>(X, w0, b0, bufA);
  const float* cur = bufA;
  float* nxt = bufB;
  for (int l = 0; l < 8; ++l) {
    conv_mfma<<<cgrid, 512, 0, stream>>>(cur, ws_mid + l * 900, bs_mid + l * 10, nxt);
    const float* t = cur; cur = nxt; nxt = (float*)t;
  }
  // cur == bufA after 8 swaps; imfeat -> bufB, cent0 -> centA
  conv_final_t32<<<cgrid, 1024, 0, stream>>>(cur, wf, bf, X, bufB, centA);

  float* aff_out = out + BB * 10 * 256;  // cent (5120) then aff
  float* nums[2] = {num0, num1};
  float* dens[2] = {den0, den1};
  for (int k = 0; k < 10; ++k) {
    iter2<<<cgrid, 256, 0, stream>>>(bufB,
        (k == 0) ? centA : nullptr,
        (k == 0) ? nullptr : nums[(k - 1) & 1],
        (k == 0) ? nullptr : dens[(k - 1) & 1],
        nums[k & 1], dens[k & 1],
        (k == 9) ? aff_out : nullptr);
  }
  cent_final<<<dim3(BB), 256, 0, stream>>>(nums[1], dens[1], out);
}

// Round 11
// 255.661 us; speedup vs baseline: 2.8775x; 1.1403x over previous
//
#include <hip/hip_runtime.h>

#define HH 512
#define WW 512
#define BB 2
#define CKXY 0.3125f   /* COMPACT / sqrt(H*W/NSUP) = 10/32 */
#define HW (HH*WW)

typedef short bf16x8 __attribute__((ext_vector_type(8)));
typedef float f32x4  __attribute__((ext_vector_type(4)));

__device__ __forceinline__ unsigned short f2bf(float f) {
  unsigned u = __float_as_uint(f);
  u += 0x7FFF + ((u >> 16) & 1);   // round-to-nearest-even
  return (unsigned short)(u >> 16);
}
__device__ __forceinline__ unsigned pack2(float lo, float hi) {
  return (unsigned)f2bf(lo) | ((unsigned)f2bf(hi) << 16);
}

// ---------------- MFMA conv 3x3 CIN->10 (+relu), 32x32 tile, 512 thr.
// LDS [34][34][16ch] bf16 = 37 KB. 5 MFMA per 16-px tile (K=32 = 2 taps x 16 ci).
// Input: f32 planar (BF16IN=false) or bf16 pair-planes (BF16IN=true).
// Output: bf16 pair-planes (5 dword planes), channel pairs merged via shfl_xor(1).
template<int CIN, bool BF16IN, bool RELU>
__global__ __launch_bounds__(512) void conv_mfma_u(const void* __restrict__ in,
    const float* __restrict__ w, const float* __restrict__ bias,
    unsigned* __restrict__ outu) {
  const int bx = blockIdx.x, by = blockIdx.y, b = blockIdx.z;
  const int tid = threadIdx.x;
  const int gy0 = by * 32, gx0 = bx * 32;
  __shared__ unsigned short sT[34 * 34 * 16];

  const int lane = tid & 63;
  const int g = lane >> 4;        // k-quarter 0..3
  const int co = lane & 15;       // output channel col
  bf16x8 Bf[5];
  #pragma unroll
  for (int P = 0; P < 5; ++P) {
    #pragma unroll
    for (int j = 0; j < 8; ++j) {
      const int tap = 2 * P + (g >> 1);
      const int ci = ((g & 1) << 3) + j;
      unsigned short v = 0;
      if (co < 10 && ci < CIN && tap < 9)
        v = f2bf(w[(co * CIN + ci) * 9 + tap]);
      Bf[P][j] = (short)v;
    }
  }
  const float bs = (co < 10) ? bias[co] : 0.f;

  // ---- stage tile (halo included) as [py][px][16ch] bf16
  for (int p = tid; p < 34 * 34; p += 512) {
    const int ly = p / 34, lx = p - ly * 34;
    const int gy = gy0 + ly - 1, gx = gx0 + lx - 1;
    const bool ok = ((unsigned)gy < HH) && ((unsigned)gx < WW);
    const int pix = gy * WW + gx;
    unsigned u[8];
    if (BF16IN) {
      const unsigned* pp = (const unsigned*)in + (size_t)b * 5 * HW + pix;
      #pragma unroll
      for (int c2 = 0; c2 < 8; ++c2)
        u[c2] = (c2 < (CIN + 1) / 2 && ok) ? pp[c2 * HW] : 0u;
    } else {
      const float* pp = (const float*)in + (size_t)b * CIN * HW + pix;
      #pragma unroll
      for (int c2 = 0; c2 < 8; ++c2) {
        float f0 = (2 * c2 < CIN && ok) ? pp[(2 * c2) * HW] : 0.f;
        float f1 = (2 * c2 + 1 < CIN && ok) ? pp[(2 * c2 + 1) * HW] : 0.f;
        u[c2] = pack2(f0, f1);
      }
    }
    uint4* dst = reinterpret_cast<uint4*>(&sT[p * 16]);
    dst[0] = make_uint4(u[0], u[1], u[2], u[3]);
    dst[1] = make_uint4(u[4], u[5], u[6], u[7]);
  }
  __syncthreads();

  // ---- compute: 64 px-tiles, 8 per wave
  const int wave = tid >> 6;
  unsigned* ob = outu + (size_t)b * 5 * HW;
  for (int i = 0; i < 8; ++i) {
    const int t = wave * 8 + i;
    const int py = t >> 1;
    const int pxb = (t & 1) << 4;
    f32x4 acc = {bs, bs, bs, bs};
    #pragma unroll
    for (int P = 0; P < 5; ++P) {
      int tap = 2 * P + (g >> 1);
      if (tap > 8) tap = 8;         // phantom tap: B=0 there
      const int dy = tap / 3 - 1, dx = tap % 3 - 1;
      const int m = lane & 15;
      const int addr = ((py + 1 + dy) * 34 + (pxb + m + 1 + dx)) * 16 + ((g & 1) << 3);
      bf16x8 a = *reinterpret_cast<const bf16x8*>(&sT[addr]);
      acc = __builtin_amdgcn_mfma_f32_16x16x32_bf16(a, Bf[P], acc, 0, 0, 0);
    }
    float o0 = acc[0], o1 = acc[1], o2 = acc[2], o3 = acc[3];
    if (RELU) { o0 = fmaxf(o0, 0.f); o1 = fmaxf(o1, 0.f); o2 = fmaxf(o2, 0.f); o3 = fmaxf(o3, 0.f); }
    const float q0 = __shfl_xor(o0, 1), q1 = __shfl_xor(o1, 1);
    const float q2 = __shfl_xor(o2, 1), q3 = __shfl_xor(o3, 1);
    if (!(co & 1) && co < 10) {
      const int y = gy0 + py;
      const int x = gx0 + pxb + (g << 2);
      uint4 st;
      st.x = pack2(o0, q0); st.y = pack2(o1, q1);
      st.z = pack2(o2, q2); st.w = pack2(o3, q3);
      *reinterpret_cast<uint4*>(&ob[(co >> 1) * HW + y * WW + x]) = st;
    }
  }
}

// ---------------- final conv (10->5) via MFMA + imfeat build + cent0
// Input: bf16 pair-planes. imfeat (f32): 0..4 s1, 5..7 X, 8 x*ck, 9 y*ck.
__global__ __launch_bounds__(512) void conv_final_mfma(const unsigned* __restrict__ in,
    const float* __restrict__ w, const float* __restrict__ bias,
    const float* __restrict__ X, float* __restrict__ imfeat,
    float* __restrict__ cent0) {
  const int bx = blockIdx.x, by = blockIdx.y, b = blockIdx.z;
  const int tid = threadIdx.x;
  const int gy0 = by * 32, gx0 = bx * 32;
  __shared__ unsigned short sT[34 * 34 * 16];
  __shared__ float sC[8][5];
  __shared__ float sX[8][3];

  const int lane = tid & 63;
  const int g = lane >> 4;
  const int co = lane & 15;
  bf16x8 Bf[5];
  #pragma unroll
  for (int P = 0; P < 5; ++P) {
    #pragma unroll
    for (int j = 0; j < 8; ++j) {
      const int tap = 2 * P + (g >> 1);
      const int ci = ((g & 1) << 3) + j;
      unsigned short v = 0;
      if (co < 5 && ci < 10 && tap < 9)
        v = f2bf(w[(co * 10 + ci) * 9 + tap]);
      Bf[P][j] = (short)v;
    }
  }
  const float bs = (co < 5) ? bias[co] : 0.f;

  for (int p = tid; p < 34 * 34; p += 512) {
    const int ly = p / 34, lx = p - ly * 34;
    const int gy = gy0 + ly - 1, gx = gx0 + lx - 1;
    const bool ok = ((unsigned)gy < HH) && ((unsigned)gx < WW);
    const unsigned* pp = in + (size_t)b * 5 * HW + gy * WW + gx;
    unsigned u[5];
    #pragma unroll
    for (int c2 = 0; c2 < 5; ++c2) u[c2] = ok ? pp[c2 * HW] : 0u;
    uint4* dst = reinterpret_cast<uint4*>(&sT[p * 16]);
    dst[0] = make_uint4(u[0], u[1], u[2], u[3]);
    dst[1] = make_uint4(u[4], 0u, 0u, 0u);
  }
  __syncthreads();

  const int wave = tid >> 6;
  float* ob = imfeat + (size_t)b * 10 * HW;
  float cSum = 0.f;
  for (int i = 0; i < 8; ++i) {
    const int t = wave * 8 + i;
    const int py = t >> 1;
    const int pxb = (t & 1) << 4;
    f32x4 acc = {bs, bs, bs, bs};
    #pragma unroll
    for (int P = 0; P < 5; ++P) {
      int tap = 2 * P + (g >> 1);
      if (tap > 8) tap = 8;
      const int dy = tap / 3 - 1, dx = tap % 3 - 1;
      const int m = lane & 15;
      const int addr = ((py + 1 + dy) * 34 + (pxb + m + 1 + dx)) * 16 + ((g & 1) << 3);
      bf16x8 a = *reinterpret_cast<const bf16x8*>(&sT[addr]);
      acc = __builtin_amdgcn_mfma_f32_16x16x32_bf16(a, Bf[P], acc, 0, 0, 0);
    }
    if (co < 5) {
      const int y = gy0 + py;
      const int x = gx0 + pxb + (g << 2);
      float4 o; o.x = acc[0]; o.y = acc[1]; o.z = acc[2]; o.w = acc[3];
      *reinterpret_cast<float4*>(&ob[co * HW + y * WW + x]) = o;
    }
    cSum += acc[0] + acc[1] + acc[2] + acc[3];
  }
  // reduce cSum over the 4 k-quarter lanes sharing co (xor 16, 32)
  cSum += __shfl_xor(cSum, 16);
  cSum += __shfl_xor(cSum, 32);
  if (lane < 5) sC[wave][lane] = cSum;

  // X passthrough + coords + ch5..7 sums (2 px per thread)
  const float* Xb = X + (size_t)b * 3 * HW;
  float xs[3] = {0.f, 0.f, 0.f};
  for (int p = tid; p < 1024; p += 512) {
    const int y = gy0 + (p >> 5), x = gx0 + (p & 31);
    const int pix = y * WW + x;
    #pragma unroll
    for (int c = 0; c < 3; ++c) {
      float v = Xb[c * HW + pix];
      ob[(5 + c) * HW + pix] = v;
      xs[c] += v;
    }
    ob[8 * HW + pix] = (float)x * CKXY;
    ob[9 * HW + pix] = (float)y * CKXY;
  }
  #pragma unroll
  for (int off = 32; off; off >>= 1) {
    #pragma unroll
    for (int c = 0; c < 3; ++c) xs[c] += __shfl_down(xs[c], off);
  }
  if (lane == 0) {
    #pragma unroll
    for (int c = 0; c < 3; ++c) sX[wave][c] = xs[c];
  }
  __syncthreads();
  if (tid < 5) {
    float s = 0.f;
    #pragma unroll
    for (int wv = 0; wv < 8; ++wv) s += sC[wv][tid];
    cent0[((b * 10 + tid) * 16 + by) * 16 + bx] = s * (1.0f / 1024.0f);
  }
  if (tid >= 64 && tid < 67) {
    const int c = tid - 64;
    float s = 0.f;
    #pragma unroll
    for (int wv = 0; wv < 8; ++wv) s += sX[wv][c];
    cent0[((b * 10 + 5 + c) * 16 + by) * 16 + bx] = s * (1.0f / 1024.0f);
  }
  if (tid == 128) cent0[((b * 10 + 8) * 16 + by) * 16 + bx] = ((float)gx0 + 15.5f) * CKXY;
  if (tid == 129) cent0[((b * 10 + 9) * 16 + by) * 16 + bx] = ((float)gy0 + 15.5f) * CKXY;
}

// -------------------- SSN iteration: (optional in-block centroid) + aff + sums
__global__ __launch_bounds__(256) void iter2(const float* __restrict__ imfeat,
    const float* __restrict__ centIn, const float* __restrict__ numP,
    const float* __restrict__ denP, float* __restrict__ numO,
    float* __restrict__ denO, float* __restrict__ affO) {
  const int cx = blockIdx.x, cy = blockIdx.y, b = blockIdx.z;
  const int tid = threadIdx.x;
  __shared__ float sc[9][10];
  __shared__ float nb[9][11];
  if (centIn) {
    if (tid < 90) {
      int s = tid / 10, ch = tid - s * 10;
      int dr = s / 3 - 1, dc = s % 3 - 1;
      int r = min(max(cy + dr, 0), 15), c = min(max(cx + dc, 0), 15);
      sc[s][ch] = centIn[((b * 10 + ch) * 16 + r) * 16 + c];
    }
    __syncthreads();
  } else {
    if (tid < 99) {
      int s = tid / 11, j = tid - s * 11;
      int dr = s / 3 - 1, dc = s % 3 - 1;
      int r = min(max(cy + dr, 0), 15), c = min(max(cx + dc, 0), 15);
      float a = 0.f;
      #pragma unroll
      for (int rr = -1; rr <= 1; ++rr)
        #pragma unroll
        for (int cc = -1; cc <= 1; ++cc) {
          int R = r + rr, C = c + cc;
          if ((unsigned)R < 16u && (unsigned)C < 16u)
            a += (j < 10) ? numP[((b * 10 + j) * 16 + R) * 16 + C]
                          : denP[(b * 16 + R) * 16 + C];
        }
      nb[s][j] = a;
    }
    __syncthreads();
    if (tid < 90) {
      int s = tid / 10, ch = tid - s * 10;
      sc[s][ch] = nb[s][ch] / nb[s][10];
    }
    __syncthreads();
  }

  float accN[10];
  #pragma unroll
  for (int ch = 0; ch < 10; ++ch) accN[ch] = 0.f;
  float accD = 0.f;
  const int col = tid & 31, row0 = tid >> 5;
  for (int p = 0; p < 4; ++p) {
    const int y = cy * 32 + row0 + p * 8;
    const int x = cx * 32 + col;
    float f[10];
    #pragma unroll
    for (int ch = 0; ch < 10; ++ch)
      f[ch] = imfeat[((b * 10 + ch) * HH + y) * WW + x];
    float asum = 0.f;
    #pragma unroll
    for (int s = 0; s < 9; ++s) {
      float ss = 0.f;
      #pragma unroll
      for (int ch = 0; ch < 10; ++ch) { float d = f[ch] - sc[s][ch]; ss = fmaf(d, d, ss); }
      float a = __expf(-ss * (1.0f / 1000.0f));
      asum += a;
      if (affO) affO[((b * 9 + s) * HH + y) * WW + x] = a;
    }
    accD += asum;
    #pragma unroll
    for (int ch = 0; ch < 10; ++ch) accN[ch] = fmaf(f[ch], asum, accN[ch]);
  }
  #pragma unroll
  for (int off = 32; off; off >>= 1) {
    accD += __shfl_down(accD, off);
    #pragma unroll
    for (int ch = 0; ch < 10; ++ch) accN[ch] += __shfl_down(accN[ch], off);
  }
  __shared__ float sPart[4][11];
  const int wave = tid >> 6, lane = tid & 63;
  if (lane == 0) {
    #pragma unroll
    for (int ch = 0; ch < 10; ++ch) sPart[wave][ch] = accN[ch];
    sPart[wave][10] = accD;
  }
  __syncthreads();
  if (tid < 11) {
    float s = sPart[0][tid] + sPart[1][tid] + sPart[2][tid] + sPart[3][tid];
    if (tid < 10) numO[((b * 10 + tid) * 16 + cy) * 16 + cx] = s;
    else denO[(b * 16 + cy) * 16 + cx] = s;
  }
}

// ------------------------------- final cent = box3(num)/box3(den) -> output
__global__ __launch_bounds__(256) void cent_final(const float* __restrict__ num_bs,
    const float* __restrict__ den_bs, float* __restrict__ out_cent) {
  const int b = blockIdx.x;
  const int tid = threadIdx.x;
  const int cy = tid >> 4, cx = tid & 15;
  float den = 0.f;
  #pragma unroll
  for (int dr = -1; dr <= 1; ++dr)
    #pragma unroll
    for (int dc = -1; dc <= 1; ++dc) {
      int r = cy + dr, c = cx + dc;
      if ((unsigned)r < 16 && (unsigned)c < 16) den += den_bs[(b * 16 + r) * 16 + c];
    }
  #pragma unroll
  for (int ch = 0; ch < 10; ++ch) {
    float num = 0.f;
    #pragma unroll
    for (int dr = -1; dr <= 1; ++dr)
      #pragma unroll
      for (int dc = -1; dc <= 1; ++dc) {
        int r = cy + dr, c = cx + dc;
        if ((unsigned)r < 16 && (unsigned)c < 16)
          num += num_bs[((b * 10 + ch) * 16 + r) * 16 + c];
      }
    float invck = (ch >= 8) ? (1.0f / CKXY) : 1.0f;
    out_cent[((b * 10 + ch) * 16 + cy) * 16 + cx] = (num / den) * invck;
  }
}

// ---------------------------------------------------------------------------
extern "C" void kernel_launch(void* const* d_in, const int* in_sizes, int n_in,
                              void* d_out, int out_size, void* d_ws, size_t ws_size,
                              hipStream_t stream) {
  const float* X      = (const float*)d_in[0];
  const float* w0     = (const float*)d_in[1];
  const float* b0     = (const float*)d_in[2];
  const float* ws_mid = (const float*)d_in[3];
  const float* bs_mid = (const float*)d_in[4];
  const float* wf     = (const float*)d_in[5];
  const float* bf     = (const float*)d_in[6];
  float* out = (float*)d_out;

  const size_t uplane = (size_t)BB * 5 * HW;    // bf16 pair-planes (dwords)
  unsigned* uA   = (unsigned*)d_ws;
  unsigned* uB   = uA + uplane;
  float* imfeat  = (float*)(uB + uplane);
  float* num0    = imfeat + (size_t)BB * 10 * HW;
  float* den0    = num0 + BB * 10 * 256;
  float* num1    = den0 + BB * 256;
  float* den1    = num1 + BB * 10 * 256;
  float* centA   = den1 + BB * 256;

  dim3 cgrid(16, 16, BB);   // 32x32 tiles
  conv_mfma_u<3, false, true><<<cgrid, 512, 0, stream>>>(X, w0, b0, uA);
  const unsigned* cur = uA;
  unsigned* nxt = uB;
  for (int l = 0; l < 8; ++l) {
    conv_mfma_u<10, true, true><<<cgrid, 512, 0, stream>>>(cur, ws_mid + l * 900, bs_mid + l * 10, nxt);
    const unsigned* t = cur; cur = nxt; nxt = (unsigned*)t;
  }
  // cur == uA after 8 swaps
  conv_final_mfma<<<cgrid, 512, 0, stream>>>(cur, wf, bf, X, imfeat, centA);

  float* aff_out = out + BB * 10 * 256;  // cent (5120) then aff
  float* nums[2] = {num0, num1};
  float* dens[2] = {den0, den1};
  for (int k = 0; k < 10; ++k) {
    iter2<<<cgrid, 256, 0, stream>>>(imfeat,
        (k == 0) ? centA : nullptr,
        (k == 0) ? nullptr : nums[(k - 1) & 1],
        (k == 0) ? nullptr : dens[(k - 1) & 1],
        nums[k & 1], dens[k & 1],
        (k == 9) ? aff_out : nullptr);
  }
  cent_final<<<dim3(BB), 256, 0, stream>>>(nums[1], dens[1], out);
}